// Round 11
// baseline (187.219 us; speedup 1.0000x reference)
//
#include <hip/hip_runtime.h>
#include <cstdint>
#include <cstddef>

#define Bn 64
#define Tn 2048
#define Un 512
#define QSn 512
#define MSn 512
#define TCH 64
#define NCH 32   // chunks per batch = Tn/TCH
#define NKT 16   // K-tiles: 512 / BK, BK = 32

using f32x16 = __attribute__((ext_vector_type(16))) float;
using bf16x8 = __attribute__((ext_vector_type(8))) short;

__device__ __forceinline__ unsigned short f2bf(float x) {
    unsigned int u = __float_as_uint(x);
    u += 0x7FFFu + ((u >> 16) & 1u);
    return (unsigned short)(u >> 16);
}

__device__ __forceinline__ unsigned int pk2bf(float lo, float hi) {
    unsigned int r;
    asm("v_cvt_pk_bf16_f32 %0, %1, %2" : "=v"(r) : "v"(lo), "v"(hi));
    return r;
}

__device__ __forceinline__ bf16x8 cvt8(float4 a, float4 b) {
    union { unsigned int u[4]; bf16x8 v; } r;
    r.u[0] = pk2bf(a.x, a.y);
    r.u[1] = pk2bf(a.z, a.w);
    r.u[2] = pk2bf(b.x, b.y);
    r.u[3] = pk2bf(b.z, b.w);
    return r.v;
}

__device__ __forceinline__ float tanh_fast(float x) {
    float e = exp2f(x * 2.885390043258667f);   // e^{2x}
    return 1.f - 2.f * __builtin_amdgcn_rcpf(e + 1.f);
}

// async global->LDS, 16B per lane; LDS dest = wave-uniform base + lane*16
#define GLOAD(G, L) __builtin_amdgcn_global_load_lds( \
    (const __attribute__((address_space(1))) void*)(G), \
    (__attribute__((address_space(3))) void*)(L), 16, 0, 0)

// ---------------- Wm f32 -> bf16 pre-convert ----------------
__global__ __launch_bounds__(256) void cvt_kernel(const float* __restrict__ src,
                                                  unsigned short* __restrict__ dst) {
    int i = blockIdx.x * 256 + threadIdx.x;  // one float4 per thread
    float4 v = *(const float4*)(src + (size_t)i * 4);
    ushort4 h = { f2bf(v.x), f2bf(v.y), f2bf(v.z), f2bf(v.w) };
    *(ushort4*)&dst[(size_t)i * 4] = h;
}

// ---------------- pq = query @ Wq^T : [B,U] ----------------
__global__ __launch_bounds__(128) void pq_kernel(const float* __restrict__ query,
                                                 const float* __restrict__ Wq,
                                                 float* __restrict__ pq) {
    __shared__ float ql[QSn];
    const int b = blockIdx.x;
    const int quad = blockIdx.y;
    const int tid = threadIdx.x;
    for (int i = tid; i < QSn; i += 128) ql[i] = query[(size_t)b * QSn + i];
    __syncthreads();
    const int u = quad * 128 + tid;
    const float* w = Wq + (size_t)u * QSn;
    float a0 = 0.f, a1 = 0.f;
    #pragma unroll 4
    for (int k = 0; k < QSn; k += 8) {
        float4 w0 = *(const float4*)(w + k);
        float4 w1 = *(const float4*)(w + k + 4);
        float4 q0 = *(const float4*)(ql + k);
        float4 q1 = *(const float4*)(ql + k + 4);
        a0 += w0.x * q0.x + w0.y * q0.y + w0.z * q0.z + w0.w * q0.w;
        a1 += w1.x * q1.x + w1.y * q1.y + w1.z * q1.z + w1.w * q1.w;
    }
    pq[(size_t)b * Un + u] = a0 + a1;
}

// ---------------- fused score+softmax+context (v11: wave-private B) ----------
// Block = (b, 64-t chunk), 256 thr = 4 waves. Wave w owns u-slice
// [w*128, w*128+128): acc[2 mf][4 nf] (128 regs). BK=32, 16 kt.
// B: each wave GLOADs ITS OWN 128 rows -> wave-private LDS dbuf (8KB x 2).
//    No cross-wave dependency => no barrier for B; sync = counted vmcnt.
// A: 64t x 32k staged f32-regs -> cvt_pk -> shared LDS dbuf (4KB x 2).
//    ONE lgkm-only barrier per kt.
// Layout (A and B): row-pair interleaved 128B blocks, granule g = kg*2+(row&1),
// phys = g ^ (rowpair&7)  -> 2 lanes/bank on all reads/writes (free).
// vmcnt discipline per kt: issue A(kt+1)[2] then B(kt+1)[8];
//   MFMA head: vmcnt(10)  (drains B(kt), leaves new 10 in flight)
//   cvt head:  vmcnt(8)   (drains A(kt+1), leaves B(kt+1) in flight)
__global__ __launch_bounds__(256, 2) void fused_kernel(const float* __restrict__ keys,
                                                       const unsigned short* __restrict__ WmB,
                                                       const float* __restrict__ pq,
                                                       const float* __restrict__ Wa,
                                                       float* __restrict__ score_out,
                                                       float* __restrict__ pm,
                                                       float* __restrict__ pl,
                                                       float* __restrict__ pctx) {
    __shared__ __align__(16) unsigned short Ah[2][TCH * 32];      // 8 KB
    __shared__ __align__(16) unsigned short Bh[4][2][128 * 32];   // 64 KB
    __shared__ float sc_lds[4][TCH];
    __shared__ float stot[TCH];
    __shared__ float wexp[TCH];

    const int tid = threadIdx.x;
    const int lane = tid & 63;
    const int w = tid >> 6;
    const int lc = lane & 31;
    const int l5 = lane >> 5;
    const int b = blockIdx.y;
    const int chunk = blockIdx.x;
    const int t0 = chunk * TCH;

    // ---- A staging: thread owns (row = tid>>2, k-granule kg = tid&3)
    const int arow = tid >> 2;
    const int akg = tid & 3;
    const int awof = (tid >> 3) * 64 +
                     ((((akg << 1) | (arow & 1)) ^ ((tid >> 3) & 7)) * 8);
    const float* gA = keys + ((size_t)b * Tn + t0 + arow) * MSn + akg * 8;

    // ---- B staging source (swizzle folded into global address; LDS linear)
    // GLOAD j, lane l -> linear LDS (j*1024 + l*16) = rowpair rp=j*8+(l>>3),
    // phys granule l&7; logical g = (l&7)^(l>>3); row = rp*2+(g&1), kg = g>>1.
    const int bg = (lane & 7) ^ ((lane >> 3) & 7);
    const size_t bloff = (size_t)(((lane >> 3) << 1) | (bg & 1)) * MSn + (bg >> 1) * 8;
    const unsigned short* gBw = WmB + (size_t)(w * 128) * MSn + bloff;
    char* bD = (char*)&Bh[w][0][0];

    f32x16 acc[2][4];
    #pragma unroll
    for (int mf = 0; mf < 2; ++mf)
        #pragma unroll
        for (int nf = 0; nf < 4; ++nf)
            #pragma unroll
            for (int r = 0; r < 16; ++r) acc[mf][nf][r] = 0.f;

    float4 a0, a1;

    // ---- prologue: A(0) loads, B(0) GLOADs, cvt+write A(0), barrier
    a0 = *(const float4*)(gA);
    a1 = *(const float4*)(gA + 4);
    __builtin_amdgcn_sched_barrier(0);
    #pragma unroll
    for (int j = 0; j < 8; ++j)
        GLOAD(gBw + (size_t)j * 16 * MSn, bD + j * 1024);
    __builtin_amdgcn_sched_barrier(0);
    asm volatile("s_waitcnt vmcnt(8)" ::: "memory");
    __builtin_amdgcn_sched_barrier(0);
    *(bf16x8*)&Ah[0][awof] = cvt8(a0, a1);
    asm volatile("s_waitcnt lgkmcnt(0)" ::: "memory");
    __builtin_amdgcn_s_barrier();
    __builtin_amdgcn_sched_barrier(0);

    #pragma unroll
    for (int kt = 0; kt < NKT; ++kt) {
        const int cur = kt & 1;

        if (kt < NKT - 1) {
            // issue A(kt+1) FIRST (oldest of the new loads), then B(kt+1)
            const float* g = gA + (kt + 1) * 32;
            a0 = *(const float4*)(g);
            a1 = *(const float4*)(g + 4);
            __builtin_amdgcn_sched_barrier(0);
            const unsigned short* gb = gBw + (kt + 1) * 32;
            char* bdn = bD + (cur ^ 1) * 8192;
            #pragma unroll
            for (int j = 0; j < 8; ++j)
                GLOAD(gb + (size_t)j * 16 * MSn, bdn + j * 1024);
            __builtin_amdgcn_sched_barrier(0);
            asm volatile("s_waitcnt vmcnt(10)" ::: "memory");  // B(kt) landed
        } else {
            asm volatile("s_waitcnt vmcnt(0)" ::: "memory");
        }
        __builtin_amdgcn_sched_barrier(0);

        // ---- MFMA phase: A shared, B wave-private
        {
            const unsigned short* lA = &Ah[cur][0];
            const unsigned short* lB = &Bh[w][cur][0];
            #pragma unroll
            for (int ks = 0; ks < 2; ++ks) {
                bf16x8 af[2];
                #pragma unroll
                for (int mf = 0; mf < 2; ++mf) {
                    int r = mf * 32 + lc;
                    int gp = (((ks * 2 + l5) << 1) | (r & 1)) ^ ((r >> 1) & 7);
                    af[mf] = *(const bf16x8*)&lA[(r >> 1) * 64 + gp * 8];
                }
                #pragma unroll
                for (int nf = 0; nf < 4; ++nf) {
                    int ru = nf * 32 + lc;
                    int gp = (((ks * 2 + l5) << 1) | (ru & 1)) ^ ((ru >> 1) & 7);
                    bf16x8 bfr = *(const bf16x8*)&lB[(ru >> 1) * 64 + gp * 8];
                    acc[0][nf] = __builtin_amdgcn_mfma_f32_32x32x16_bf16(af[0], bfr, acc[0][nf], 0, 0, 0);
                    acc[1][nf] = __builtin_amdgcn_mfma_f32_32x32x16_bf16(af[1], bfr, acc[1][nf], 0, 0, 0);
                }
            }
        }

        if (kt < NKT - 1) {
            // cvt + write A(kt+1); only A's 2 loads drained, B(kt+1) stays out
            asm volatile("s_waitcnt vmcnt(8)" ::: "memory");
            __builtin_amdgcn_sched_barrier(0);
            *(bf16x8*)&Ah[cur ^ 1][awof] = cvt8(a0, a1);
            asm volatile("s_waitcnt lgkmcnt(0)" ::: "memory");
            __builtin_amdgcn_s_barrier();
            __builtin_amdgcn_sched_barrier(0);
        }
    }

    // ---- epilogue: score = sum_u tanh(vals + pq[u]) * Wa[u]
    // C layout: col(u)=lc, local row(t) = mf*32 + (r&3) + 8*(r>>2) + 4*l5
    float pqv[4], wav[4];
    #pragma unroll
    for (int nf = 0; nf < 4; ++nf) {
        int u = w * 128 + nf * 32 + lc;
        pqv[nf] = pq[(size_t)b * Un + u];
        wav[nf] = Wa[u];
    }
    #pragma unroll
    for (int mf = 0; mf < 2; ++mf) {
        #pragma unroll
        for (int r = 0; r < 16; ++r) {
            float s = 0.f;
            #pragma unroll
            for (int nf = 0; nf < 4; ++nf)
                s += tanh_fast(acc[mf][nf][r] + pqv[nf]) * wav[nf];
            s += __shfl_xor(s, 16);
            s += __shfl_xor(s, 8);
            s += __shfl_xor(s, 4);
            s += __shfl_xor(s, 2);
            s += __shfl_xor(s, 1);
            if (lc == 0)
                sc_lds[w][mf * 32 + (r & 3) + 8 * (r >> 2) + 4 * l5] = s;
        }
    }
    __syncthreads();
    if (tid < TCH) {
        float v = (sc_lds[0][tid] + sc_lds[1][tid]) + (sc_lds[2][tid] + sc_lds[3][tid]);
        stot[tid] = v;
        score_out[(size_t)b * Tn + t0 + tid] = v;
    }
    __syncthreads();

    // ---- chunk softmax partials on wave 0
    if (tid < 64) {
        float v = stot[tid];
        float mx = v;
        #pragma unroll
        for (int off = 32; off; off >>= 1) mx = fmaxf(mx, __shfl_xor(mx, off));
        float e = __expf(v - mx);
        wexp[tid] = e;
        float sum = e;
        #pragma unroll
        for (int off = 32; off; off >>= 1) sum += __shfl_xor(sum, off);
        if (tid == 0) {
            pm[b * NCH + chunk] = mx;
            pl[b * NCH + chunk] = sum;
        }
    }
    __syncthreads();

    // ---- ctx partial: thread owns 2 m-cols; keys rows re-read (L2-hot)
    const int c0 = tid * 2;
    const float* kp = keys + ((size_t)b * Tn + t0) * MSn + c0;
    float cx = 0.f, cy = 0.f;
    #pragma unroll 8
    for (int t = 0; t < TCH; ++t) {
        float2 kv = *(const float2*)(kp + (size_t)t * MSn);
        float wt = wexp[t];
        cx += wt * kv.x;
        cy += wt * kv.y;
    }
    float2 cacc = { cx, cy };
    *(float2*)&pctx[((size_t)(b * NCH + chunk)) * MSn + c0] = cacc;
}

// ---------------- merge chunk partials -> total_context ----------------
__global__ __launch_bounds__(512) void merge_kernel(const float* __restrict__ pm,
                                                    const float* __restrict__ pl,
                                                    const float* __restrict__ pctx,
                                                    float* __restrict__ ctx) {
    __shared__ float sm[NCH], sl[NCH];
    const int b = blockIdx.x, tid = threadIdx.x;
    if (tid < NCH) {
        sm[tid] = pm[b * NCH + tid];
        sl[tid] = pl[b * NCH + tid];
    }
    __syncthreads();
    float M = -1e30f;
    #pragma unroll
    for (int c = 0; c < NCH; ++c) M = fmaxf(M, sm[c]);
    float L = 0.f;
    #pragma unroll
    for (int c = 0; c < NCH; ++c) L += sl[c] * __expf(sm[c] - M);
    const float inv = 1.f / L;
    float acc = 0.f;
    #pragma unroll
    for (int c = 0; c < NCH; ++c)
        acc += __expf(sm[c] - M) * pctx[((size_t)(b * NCH + c)) * MSn + tid];
    ctx[(size_t)b * MSn + tid] = acc * inv;
}

extern "C" void kernel_launch(void* const* d_in, const int* in_sizes, int n_in,
                              void* d_out, int out_size, void* d_ws, size_t ws_size,
                              hipStream_t stream) {
    const float* query = (const float*)d_in[0];
    const float* keys  = (const float*)d_in[1];
    const float* Wq    = (const float*)d_in[2];
    const float* Wm    = (const float*)d_in[3];
    const float* Wa    = (const float*)d_in[4];

    float* ctx_out   = (float*)d_out;                    // [64][512]
    float* score_out = (float*)d_out + (size_t)Bn * MSn; // [64][2048]

    char* ws = (char*)d_ws;
    float* ws_pq   = (float*)(ws);                       // 128 KB
    unsigned short* ws_wmbf = (unsigned short*)(ws + 131072);  // 512 KB
    float* ws_pm   = (float*)(ws + 655360);              // 8 KB
    float* ws_pl   = (float*)(ws + 663552);              // 8 KB
    float* ws_pctx = (float*)(ws + 671744);              // 4 MB [64][32][512]

    cvt_kernel<<<(Un * MSn / 4) / 256, 256, 0, stream>>>(Wm, ws_wmbf);
    pq_kernel<<<dim3(Bn, 4), 128, 0, stream>>>(query, Wq, ws_pq);
    fused_kernel<<<dim3(NCH, Bn), 256, 0, stream>>>(keys, ws_wmbf, ws_pq, Wa,
                                                    score_out, ws_pm, ws_pl, ws_pctx);
    merge_kernel<<<Bn, 512, 0, stream>>>(ws_pm, ws_pl, ws_pctx, ctx_out);
}